// Round 1
// 1421.141 us; speedup vs baseline: 1.0158x; 1.0158x over previous
//
#include <hip/hip_runtime.h>

// out[b][o] = sum_k x[b][k] * W[o][k];  B=2^20, K=256, O=64, fp32 in/out.
// Memory-bound: 1.342 GB mandatory HBM traffic -> ~213us floor @ 6.3 TB/s.
// bf16 MFMA 16x16x32, OPERAND-SWAPPED: acc = mfma(Wfrag, xfrag) so D is
// out^T-layout (row = output channel, col = batch row). Each lane then holds
// 4 consecutive output channels of one batch row -> float4 stores (4/tile
// instead of 64 scalar). Conversions use native __bf16 casts
// (v_cvt_pk_bf16_f32) instead of hand-rolled bit ops. A-fragments staged as
// bf16 (32 VGPR) not raw f32 (64 VGPR): total live ~190 VGPR < 256 cap, so
// the compiler can hoist next-tile loads across the loop (2 waves/SIMD).

typedef __bf16 bf16x8 __attribute__((ext_vector_type(8)));
typedef float floatx4 __attribute__((ext_vector_type(4)));

#define KDIM    256
#define NDIM    64
#define NBLOCKS 512
#define TPB     256
#define NWAVES  (NBLOCKS * (TPB / 64))   // 2048
#define NTILES  ((1u << 20) / 16)        // 65536 row-tiles, 32 tiles/wave

__device__ __forceinline__ bf16x8 cvt8(float4 a, float4 b) {
    // native casts -> compiler emits v_cvt_pk_bf16_f32 (RNE), 2 elems/instr
    bf16x8 r;
    r[0] = (__bf16)a.x; r[1] = (__bf16)a.y; r[2] = (__bf16)a.z; r[3] = (__bf16)a.w;
    r[4] = (__bf16)b.x; r[5] = (__bf16)b.y; r[6] = (__bf16)b.z; r[7] = (__bf16)b.w;
    return r;
}

__global__ __launch_bounds__(TPB, 2) void NN_38010460570161_kernel(
    const float* __restrict__ x, const float* __restrict__ W,
    float* __restrict__ out)
{
    const int lane = threadIdx.x & 63;
    const int n = lane & 15;   // batch row within tile (B-col) / W-row (A-row)
    const int q = lane >> 4;   // quad: k-offset group; D-row group (o channels)
    const int wid = blockIdx.x * (TPB / 64) + (threadIdx.x >> 6);

    // ---- A operand: Wfrag[nt][ks][j] = W[nt*16+n][ks*32+q*8+j] (128 VGPR) ----
    bf16x8 wfrag[4][8];
#pragma unroll
    for (int nt = 0; nt < 4; ++nt) {
        const float* wb = W + (nt * 16 + n) * KDIM + q * 8;
#pragma unroll
        for (int ks = 0; ks < 8; ++ks) {
            float4 w0 = *(const float4*)(wb + ks * 32);
            float4 w1 = *(const float4*)(wb + ks * 32 + 4);
            wfrag[nt][ks] = cvt8(w0, w1);
        }
    }

    // ---- main streaming loop over 16-row tiles ----
    for (unsigned t = wid; t < NTILES; t += NWAVES) {
        // B operand: af[ks][j] = x[t*16+n][ks*32+q*8+j], staged as bf16 (32 VGPR)
        const float* xb = x + ((size_t)t * 16 + n) * KDIM + q * 8;
        bf16x8 af[8];
#pragma unroll
        for (int ks = 0; ks < 8; ++ks) {
            float4 p0 = *(const float4*)(xb + ks * 32);
            float4 p1 = *(const float4*)(xb + ks * 32 + 4);
            af[ks] = cvt8(p0, p1);
        }

        floatx4 acc[4];
#pragma unroll
        for (int nt = 0; nt < 4; ++nt) acc[nt] = (floatx4){0.f, 0.f, 0.f, 0.f};

#pragma unroll
        for (int ks = 0; ks < 8; ++ks)
#pragma unroll
            for (int nt = 0; nt < 4; ++nt)
                acc[nt] = __builtin_amdgcn_mfma_f32_16x16x32_bf16(
                    wfrag[nt][ks], af[ks], acc[nt], 0, 0, 0);

        // D layout (swapped): row = q*4 + r = o_local, col = n = b_local.
        // lane (n,q) holds out[t*16+n][nt*16 + q*4 .. q*4+3] -> float4 store.
        float* ob = out + ((size_t)t * 16 + n) * NDIM + q * 4;
#pragma unroll
        for (int nt = 0; nt < 4; ++nt)
            *(floatx4*)(ob + nt * 16) = acc[nt];
    }
}

extern "C" void kernel_launch(void* const* d_in, const int* in_sizes, int n_in,
                              void* d_out, int out_size, void* d_ws, size_t ws_size,
                              hipStream_t stream) {
    const float* x = (const float*)d_in[0];    // [B, 256] fp32
    const float* W = (const float*)d_in[1];    // [64, 256] fp32
    float* out = (float*)d_out;                // [B, 64] fp32
    NN_38010460570161_kernel<<<NBLOCKS, TPB, 0, stream>>>(x, W, out);
}